// Round 3
// baseline (418.286 us; speedup 1.0000x reference)
//
#include <hip/hip_runtime.h>
#include <stdint.h>
#include <math.h>

#define BATCH 32
#define NANCH 33600
#define N0 25600   // 160x160, stride 8
#define N1 6400    // 80x80,  stride 16
#define N2 1600    // 40x40,  stride 32
#define TOPK 1000
#define NBIN 4096
#define CCAP 2816
#define DETS_SIZE (BATCH * TOPK * 5)

// numpy-exact float32 sigmoid: exp in double (correctly rounded to f32), then f32 divide.
// Needed ONLY where ranking depends on exact score bits.
__device__ __forceinline__ float sigmoid_np(float x) {
    float e = (float)::exp(-(double)x);
    return 1.0f / (1.0f + e);
}

// ---------------- Kernel 0: init rank table (-1) + global histogram (0) ----------------
__global__ void init_kernel(int* __restrict__ rank, unsigned* __restrict__ ghist) {
    int i = blockIdx.x * blockDim.x + threadIdx.x;
    if (i < BATCH * NANCH) rank[i] = -1;
    if (i < BATCH * NBIN) ghist[i] = 0u;
}

// ---------------- Kernel 1: score S = sigmoid(cls)*sigmoid(obj) + histogram -------------
__global__ void score_kernel(const float* __restrict__ cls0, const float* __restrict__ cls1,
                             const float* __restrict__ cls2,
                             const float* __restrict__ obj0, const float* __restrict__ obj1,
                             const float* __restrict__ obj2,
                             float* __restrict__ S, unsigned* __restrict__ ghist) {
    int n = blockIdx.x * blockDim.x + threadIdx.x;
    int b = blockIdx.y;
    if (n >= NANCH) return;
    const float* cp; const float* op; int nl;
    if (n < N0)            { cp = cls0 + (size_t)b * N0; op = obj0 + (size_t)b * N0; nl = n; }
    else if (n < N0 + N1)  { cp = cls1 + (size_t)b * N1; op = obj1 + (size_t)b * N1; nl = n - N0; }
    else                   { cp = cls2 + (size_t)b * N2; op = obj2 + (size_t)b * N2; nl = n - N0 - N1; }
    float sc = sigmoid_np(cp[nl]) * sigmoid_np(op[nl]);
    S[(size_t)b * NANCH + n] = sc;
    // scores in (0,1): bits>>19 < 4096
    atomicAdd(&ghist[(size_t)b * NBIN + (__float_as_uint(sc) >> 19)], 1u);
}

// ---------------- Kernel 2: exact top-1000 per batch -> rank[b][n] ------------------------
// 64-bit key = (score_bits << 32) | (0xFFFFFFFF - n): descending key order ==
// jax.lax.top_k order (descending score, ties by ascending index). Keys unique.
__global__ __launch_bounds__(1024) void select_kernel(const float* __restrict__ S_g,
                                                      const unsigned* __restrict__ ghist,
                                                      int* __restrict__ rank) {
    const int b = blockIdx.x;
    const float* S = S_g + (size_t)b * NANCH;
    __shared__ unsigned scan[1024];
    __shared__ unsigned long long wbuf[TOPK];
    __shared__ unsigned long long cbuf[CCAP];
    __shared__ unsigned sh_T, sh_above, sh_d, sh_k2, wcnt, ccnt;
    const int tid = threadIdx.x;

    if (tid == 0) { wcnt = 0u; ccnt = 0u; }
    // ---- load per-batch histogram (built by score_kernel), suffix-scan it ----
    unsigned s0 = ghist[(size_t)b * NBIN + 4 * tid + 0];
    unsigned s1 = ghist[(size_t)b * NBIN + 4 * tid + 1];
    unsigned s2 = ghist[(size_t)b * NBIN + 4 * tid + 2];
    unsigned s3 = ghist[(size_t)b * NBIN + 4 * tid + 3];
    unsigned tot = s0 + s1 + s2 + s3;
    scan[tid] = tot;
    __syncthreads();
    for (int off = 1; off < 1024; off <<= 1) {
        unsigned v = scan[tid] + ((tid + off < 1024) ? scan[tid + off] : 0u);
        __syncthreads();
        scan[tid] = v;
        __syncthreads();
    }
    unsigned excl = scan[tid] - tot;  // keys in bins > 4t+3
    {
        unsigned a3 = excl,      f3 = excl + s3;
        unsigned a2 = f3,        f2 = f3 + s2;
        unsigned a1 = f2,        f1 = f2 + s1;
        unsigned a0 = f1,        f0 = f1 + s0;
        if (a3 < TOPK && f3 >= TOPK) { sh_T = 4u * tid + 3u; sh_above = a3; }
        if (a2 < TOPK && f2 >= TOPK) { sh_T = 4u * tid + 2u; sh_above = a2; }
        if (a1 < TOPK && f1 >= TOPK) { sh_T = 4u * tid + 1u; sh_above = a1; }
        if (a0 < TOPK && f0 >= TOPK) { sh_T = 4u * tid + 0u; sh_above = a0; }
    }
    __syncthreads();
    const unsigned T = sh_T;
    const unsigned above = sh_above;     // strict winners (bins > T), < TOPK
    const unsigned need = TOPK - above;  // taken from boundary bin T

    // ---- single pass: collect strict winners + boundary candidates ----
    const float4* S4 = (const float4*)S;
    const int M4 = NANCH / 4;
    for (int i = tid; i < M4; i += 1024) {
        float4 v = S4[i];
        float c[4] = {v.x, v.y, v.z, v.w};
        #pragma unroll
        for (int q = 0; q < 4; ++q) {
            unsigned u = __float_as_uint(c[q]);
            unsigned bin = u >> 19;
            if (bin >= T) {
                unsigned n = (unsigned)(4 * i + q);
                unsigned long long key = ((unsigned long long)u << 32)
                                       | (unsigned long long)(0xFFFFFFFFu - n);
                if (bin > T) {
                    unsigned p = atomicAdd(&wcnt, 1u);
                    wbuf[p] = key;
                } else {
                    unsigned p = atomicAdd(&ccnt, 1u);
                    if (p < CCAP) cbuf[p] = key;
                }
            }
        }
    }
    __syncthreads();

    if (ccnt <= CCAP) {
        // ---- fast path: rank winners and candidates by LDS broadcast counting ----
        const int W = (int)wcnt;   // == above
        if (tid < W) {
            unsigned long long my = wbuf[tid];
            int r = 0;
            for (int j = 0; j < W; ++j) r += (wbuf[j] > my) ? 1 : 0;
            unsigned n = 0xFFFFFFFFu - (unsigned)(my & 0xFFFFFFFFULL);
            rank[(size_t)b * NANCH + n] = r;
        }
        const int C = (int)ccnt;
        if (tid < C) {
            unsigned long long my = cbuf[tid];
            int r = 0;
            for (int j = 0; j < C; ++j) r += (cbuf[j] > my) ? 1 : 0;
            if (r < (int)need) {
                unsigned n = 0xFFFFFFFFu - (unsigned)(my & 0xFFFFFFFFULL);
                rank[(size_t)b * NANCH + n] = (int)above + r;
            }
        }
    } else {
        // ---- fallback (boundary-bin overflow; not expected): 8x8-bit radix select ----
        unsigned long long prefix = 0ULL;
        unsigned k = TOPK;
        for (int pass = 7; pass >= 0; --pass) {
            if (tid < 256) scan[tid] = 0u;
            __syncthreads();
            const int shift = pass * 8;
            const unsigned long long prefmask =
                (pass == 7) ? 0ULL : (0xFFFFFFFFFFFFFFFFULL << (shift + 8));
            for (int i = tid; i < NANCH; i += 1024) {
                unsigned u = __float_as_uint(S[i]);
                unsigned long long key = ((unsigned long long)u << 32)
                                       | (unsigned long long)(0xFFFFFFFFu - (unsigned)i);
                if ((key & prefmask) == prefix)
                    atomicAdd(&scan[(unsigned)((key >> shift) & 0xFFULL)], 1u);
            }
            __syncthreads();
            if (tid == 0) {
                unsigned cum = 0; int d = 0;
                for (int v = 255; v >= 0; --v) {
                    unsigned c = scan[v];
                    if (cum + c >= k) { d = v; break; }
                    cum += c;
                }
                sh_d = (unsigned)d;
                sh_k2 = k - cum;
            }
            __syncthreads();
            prefix |= ((unsigned long long)sh_d) << shift;
            k = sh_k2;
            __syncthreads();
        }
        if (tid == 0) wcnt = 0u;
        __syncthreads();
        for (int i = tid; i < NANCH; i += 1024) {
            unsigned u = __float_as_uint(S[i]);
            unsigned long long key = ((unsigned long long)u << 32)
                                   | (unsigned long long)(0xFFFFFFFFu - (unsigned)i);
            if (key >= prefix) {
                unsigned pos = atomicAdd(&wcnt, 1u);
                wbuf[pos] = key;
            }
        }
        __syncthreads();
        const int m = (int)wcnt;   // == TOPK
        if (tid < m) {
            unsigned long long my = wbuf[tid];
            int r = 0;
            for (int j = 0; j < m; ++j) r += (wbuf[j] > my) ? 1 : 0;
            unsigned n = 0xFFFFFFFFu - (unsigned)(my & 0xFFFFFFFFULL);
            rank[(size_t)b * NANCH + n] = r;
        }
    }
}

// ---------------- Kernel 3: coalesced sweep decode ---------------------------------------
// All lanes stream all decode planes coalesced (full cache-line utilization);
// only kept lanes (rank >= 0) decode + scatter-store. Waves with no kept lane skip.
__global__ __launch_bounds__(256) void sweep_emit(
        const int* __restrict__ rank_g, const float* __restrict__ S,
        const float* __restrict__ bbox0, const float* __restrict__ bbox1,
        const float* __restrict__ bbox2,
        const float* __restrict__ kpt0, const float* __restrict__ kpt1,
        const float* __restrict__ kpt2,
        const float* __restrict__ vis0, const float* __restrict__ vis1,
        const float* __restrict__ vis2,
        float* __restrict__ out) {
    int n = blockIdx.x * 256 + threadIdx.x;
    int b = blockIdx.y;
    bool valid = (n < NANCH);
    int r = valid ? rank_g[(size_t)b * NANCH + n] : -1;
    if (__ballot(r >= 0) == 0ULL) return;   // wave-uniform skip (~14% of waves)

    int nc = valid ? n : 0;
    int nl, W, HW; float s;
    const float *bb, *kp, *vp;
    if (nc < N0) {
        nl = nc;            W = 160; HW = N0; s = 8.f;
        bb = bbox0; kp = kpt0; vp = vis0;
    } else if (nc < N0 + N1) {
        nl = nc - N0;       W = 80;  HW = N1; s = 16.f;
        bb = bbox1; kp = kpt1; vp = vis1;
    } else {
        nl = nc - N0 - N1;  W = 40;  HW = N2; s = 32.f;
        bb = bbox2; kp = kpt2; vp = vis2;
    }
    float px = (float)(nl % W) * s;
    float py = (float)(nl / W) * s;

    // coalesced loads for ALL lanes; stores predicated on r >= 0
    float score = S[(size_t)b * NANCH + nc];
    float bx = bb[((size_t)b * 4 + 0) * HW + nl];
    float by = bb[((size_t)b * 4 + 1) * HW + nl];
    float bw = bb[((size_t)b * 4 + 2) * HW + nl];
    float bh = bb[((size_t)b * 4 + 3) * HW + nl];
    if (r >= 0) {
        float cx = bx * s + px;
        float cy = by * s + py;
        float hw_ = expf(bw) * s * 0.5f;
        float hh  = expf(bh) * s * 0.5f;
        float* o = out + ((size_t)b * TOPK + r) * 5;
        o[0] = cx - hw_;
        o[1] = cy - hh;
        o[2] = cx + hw_;
        o[3] = cy + hh;
        o[4] = score;
    }
    float* ok = out + DETS_SIZE + ((size_t)b * TOPK + (size_t)(r < 0 ? 0 : r)) * 51;
    for (int k = 0; k < 17; ++k) {
        float xk = kp[((size_t)b * 34 + 2 * k    ) * HW + nl];
        float yk = kp[((size_t)b * 34 + 2 * k + 1) * HW + nl];
        float vv = vp[((size_t)b * 17 + k        ) * HW + nl];
        if (r >= 0) {
            ok[3 * k + 0] = xk * s + px;
            ok[3 * k + 1] = yk * s + py;
            ok[3 * k + 2] = 1.0f / (1.0f + expf(-vv));  // value-only: expf is fine
        }
    }
}

extern "C" void kernel_launch(void* const* d_in, const int* in_sizes, int n_in,
                              void* d_out, int out_size, void* d_ws, size_t ws_size,
                              hipStream_t stream) {
    const float* cls0  = (const float*)d_in[0];
    const float* cls1  = (const float*)d_in[1];
    const float* cls2  = (const float*)d_in[2];
    const float* bbox0 = (const float*)d_in[3];
    const float* bbox1 = (const float*)d_in[4];
    const float* bbox2 = (const float*)d_in[5];
    const float* obj0  = (const float*)d_in[6];
    const float* obj1  = (const float*)d_in[7];
    const float* obj2  = (const float*)d_in[8];
    const float* kpt0  = (const float*)d_in[9];
    const float* kpt1  = (const float*)d_in[10];
    const float* kpt2  = (const float*)d_in[11];
    const float* vis0  = (const float*)d_in[12];
    const float* vis1  = (const float*)d_in[13];
    const float* vis2  = (const float*)d_in[14];
    float* out = (float*)d_out;

    char* ws = (char*)d_ws;
    float*    S     = (float*)ws;                                   ws += (size_t)BATCH * NANCH * sizeof(float);
    int*      rank  = (int*)ws;                                     ws += (size_t)BATCH * NANCH * sizeof(int);
    unsigned* ghist = (unsigned*)ws;

    const int initN = BATCH * NANCH;
    init_kernel<<<(initN + 255) / 256, 256, 0, stream>>>(rank, ghist);

    dim3 g1((NANCH + 255) / 256, BATCH);
    score_kernel<<<g1, 256, 0, stream>>>(cls0, cls1, cls2, obj0, obj1, obj2, S, ghist);

    select_kernel<<<BATCH, 1024, 0, stream>>>(S, ghist, rank);

    sweep_emit<<<g1, 256, 0, stream>>>(rank, S,
        bbox0, bbox1, bbox2, kpt0, kpt1, kpt2, vis0, vis1, vis2, out);
}

// Round 4
// 310.204 us; speedup vs baseline: 1.3484x; 1.3484x over previous
//
#include <hip/hip_runtime.h>
#include <stdint.h>
#include <math.h>

#define BATCH 32
#define NANCH 33600
#define N0 25600   // 160x160, stride 8
#define N1 6400    // 80x80,  stride 16
#define N2 1600    // 40x40,  stride 32
#define TOPK 1000
#define NBIN 4096
#define CCAP 2816
#define SB 4096    // anchors per score block
#define DETS_SIZE (BATCH * TOPK * 5)

// numpy-exact float32 sigmoid: exp in double (correctly rounded to f32), then f32 divide.
// Needed ONLY where ranking depends on exact score bits.
__device__ __forceinline__ float sigmoid_np(float x) {
    float e = (float)::exp(-(double)x);
    return 1.0f / (1.0f + e);
}

// ---------------- Kernel 0: init rank table (-1) + global histogram (0) ----------------
__global__ void init_kernel(int* __restrict__ rank, unsigned* __restrict__ ghist) {
    int i = blockIdx.x * blockDim.x + threadIdx.x;
    if (i < BATCH * NANCH) rank[i] = -1;
    if (i < BATCH * NBIN) ghist[i] = 0u;
}

// ---------------- Kernel 1: score S = sigmoid(cls)*sigmoid(obj) + LDS histogram ---------
// Per-block 4096-bin LDS histogram, flushed with one global atomic per NON-ZERO bin.
// (Round-3 lesson: raw global atomics on clustered bins serialized cross-XCD -> 120 us.)
__global__ __launch_bounds__(1024) void score_kernel(
        const float* __restrict__ cls0, const float* __restrict__ cls1,
        const float* __restrict__ cls2,
        const float* __restrict__ obj0, const float* __restrict__ obj1,
        const float* __restrict__ obj2,
        float* __restrict__ S, unsigned* __restrict__ ghist) {
    __shared__ unsigned hist[NBIN];
    const int tid = threadIdx.x;
    const int b = blockIdx.y;
    const int base = blockIdx.x * SB;
    for (int i = tid; i < NBIN; i += 1024) hist[i] = 0u;
    __syncthreads();

    #pragma unroll
    for (int q = 0; q < SB / 1024; ++q) {
        int n = base + q * 1024 + tid;
        if (n < NANCH) {
            const float* cp; const float* op; int nl;
            if (n < N0)            { cp = cls0 + (size_t)b * N0; op = obj0 + (size_t)b * N0; nl = n; }
            else if (n < N0 + N1)  { cp = cls1 + (size_t)b * N1; op = obj1 + (size_t)b * N1; nl = n - N0; }
            else                   { cp = cls2 + (size_t)b * N2; op = obj2 + (size_t)b * N2; nl = n - N0 - N1; }
            float sc = sigmoid_np(cp[nl]) * sigmoid_np(op[nl]);
            S[(size_t)b * NANCH + n] = sc;
            atomicAdd(&hist[__float_as_uint(sc) >> 19], 1u);  // LDS atomic
        }
    }
    __syncthreads();
    for (int i = tid; i < NBIN; i += 1024) {
        unsigned c = hist[i];
        if (c) atomicAdd(&ghist[(size_t)b * NBIN + i], c);
    }
}

// ---------------- Kernel 2: exact top-1000 per batch -> rank[b][n] ------------------------
// 64-bit key = (score_bits << 32) | (0xFFFFFFFF - n): descending key order ==
// jax.lax.top_k order (descending score, ties by ascending index). Keys unique.
__global__ __launch_bounds__(1024) void select_kernel(const float* __restrict__ S_g,
                                                      const unsigned* __restrict__ ghist,
                                                      int* __restrict__ rank) {
    const int b = blockIdx.x;
    const float* S = S_g + (size_t)b * NANCH;
    __shared__ unsigned scan[1024];
    __shared__ unsigned long long wbuf[TOPK];
    __shared__ unsigned long long cbuf[CCAP];
    __shared__ unsigned sh_T, sh_above, sh_d, sh_k2, wcnt, ccnt;
    const int tid = threadIdx.x;

    if (tid == 0) { wcnt = 0u; ccnt = 0u; }
    // ---- load per-batch histogram (built by score_kernel), suffix-scan it ----
    unsigned s0 = ghist[(size_t)b * NBIN + 4 * tid + 0];
    unsigned s1 = ghist[(size_t)b * NBIN + 4 * tid + 1];
    unsigned s2 = ghist[(size_t)b * NBIN + 4 * tid + 2];
    unsigned s3 = ghist[(size_t)b * NBIN + 4 * tid + 3];
    unsigned tot = s0 + s1 + s2 + s3;
    scan[tid] = tot;
    __syncthreads();
    for (int off = 1; off < 1024; off <<= 1) {
        unsigned v = scan[tid] + ((tid + off < 1024) ? scan[tid + off] : 0u);
        __syncthreads();
        scan[tid] = v;
        __syncthreads();
    }
    unsigned excl = scan[tid] - tot;  // keys in bins > 4t+3
    {
        unsigned a3 = excl,      f3 = excl + s3;
        unsigned a2 = f3,        f2 = f3 + s2;
        unsigned a1 = f2,        f1 = f2 + s1;
        unsigned a0 = f1,        f0 = f1 + s0;
        if (a3 < TOPK && f3 >= TOPK) { sh_T = 4u * tid + 3u; sh_above = a3; }
        if (a2 < TOPK && f2 >= TOPK) { sh_T = 4u * tid + 2u; sh_above = a2; }
        if (a1 < TOPK && f1 >= TOPK) { sh_T = 4u * tid + 1u; sh_above = a1; }
        if (a0 < TOPK && f0 >= TOPK) { sh_T = 4u * tid + 0u; sh_above = a0; }
    }
    __syncthreads();
    const unsigned T = sh_T;
    const unsigned above = sh_above;     // strict winners (bins > T), < TOPK
    const unsigned need = TOPK - above;  // taken from boundary bin T

    // ---- single pass: collect strict winners + boundary candidates ----
    const float4* S4 = (const float4*)S;
    const int M4 = NANCH / 4;
    for (int i = tid; i < M4; i += 1024) {
        float4 v = S4[i];
        float c[4] = {v.x, v.y, v.z, v.w};
        #pragma unroll
        for (int q = 0; q < 4; ++q) {
            unsigned u = __float_as_uint(c[q]);
            unsigned bin = u >> 19;
            if (bin >= T) {
                unsigned n = (unsigned)(4 * i + q);
                unsigned long long key = ((unsigned long long)u << 32)
                                       | (unsigned long long)(0xFFFFFFFFu - n);
                if (bin > T) {
                    unsigned p = atomicAdd(&wcnt, 1u);
                    wbuf[p] = key;
                } else {
                    unsigned p = atomicAdd(&ccnt, 1u);
                    if (p < CCAP) cbuf[p] = key;
                }
            }
        }
    }
    __syncthreads();

    if (ccnt <= CCAP) {
        // ---- fast path: rank winners and candidates by LDS broadcast counting ----
        const int W = (int)wcnt;   // == above
        if (tid < W) {
            unsigned long long my = wbuf[tid];
            int r = 0;
            for (int j = 0; j < W; ++j) r += (wbuf[j] > my) ? 1 : 0;
            unsigned n = 0xFFFFFFFFu - (unsigned)(my & 0xFFFFFFFFULL);
            rank[(size_t)b * NANCH + n] = r;
        }
        const int C = (int)ccnt;
        if (tid < C) {
            unsigned long long my = cbuf[tid];
            int r = 0;
            for (int j = 0; j < C; ++j) r += (cbuf[j] > my) ? 1 : 0;
            if (r < (int)need) {
                unsigned n = 0xFFFFFFFFu - (unsigned)(my & 0xFFFFFFFFULL);
                rank[(size_t)b * NANCH + n] = (int)above + r;
            }
        }
    } else {
        // ---- fallback (boundary-bin overflow; not expected): 8x8-bit radix select ----
        unsigned long long prefix = 0ULL;
        unsigned k = TOPK;
        for (int pass = 7; pass >= 0; --pass) {
            if (tid < 256) scan[tid] = 0u;
            __syncthreads();
            const int shift = pass * 8;
            const unsigned long long prefmask =
                (pass == 7) ? 0ULL : (0xFFFFFFFFFFFFFFFFULL << (shift + 8));
            for (int i = tid; i < NANCH; i += 1024) {
                unsigned u = __float_as_uint(S[i]);
                unsigned long long key = ((unsigned long long)u << 32)
                                       | (unsigned long long)(0xFFFFFFFFu - (unsigned)i);
                if ((key & prefmask) == prefix)
                    atomicAdd(&scan[(unsigned)((key >> shift) & 0xFFULL)], 1u);
            }
            __syncthreads();
            if (tid == 0) {
                unsigned cum = 0; int d = 0;
                for (int v = 255; v >= 0; --v) {
                    unsigned c = scan[v];
                    if (cum + c >= k) { d = v; break; }
                    cum += c;
                }
                sh_d = (unsigned)d;
                sh_k2 = k - cum;
            }
            __syncthreads();
            prefix |= ((unsigned long long)sh_d) << shift;
            k = sh_k2;
            __syncthreads();
        }
        if (tid == 0) wcnt = 0u;
        __syncthreads();
        for (int i = tid; i < NANCH; i += 1024) {
            unsigned u = __float_as_uint(S[i]);
            unsigned long long key = ((unsigned long long)u << 32)
                                   | (unsigned long long)(0xFFFFFFFFu - (unsigned)i);
            if (key >= prefix) {
                unsigned pos = atomicAdd(&wcnt, 1u);
                wbuf[pos] = key;
            }
        }
        __syncthreads();
        const int m = (int)wcnt;   // == TOPK
        if (tid < m) {
            unsigned long long my = wbuf[tid];
            int r = 0;
            for (int j = 0; j < m; ++j) r += (wbuf[j] > my) ? 1 : 0;
            unsigned n = 0xFFFFFFFFu - (unsigned)(my & 0xFFFFFFFFULL);
            rank[(size_t)b * NANCH + n] = r;
        }
    }
}

// ---------------- Kernel 3: coalesced sweep decode ---------------------------------------
// All lanes stream all decode planes coalesced (full cache-line utilization);
// only kept lanes (rank >= 0) decode + scatter-store. Waves with no kept lane skip.
__global__ __launch_bounds__(256) void sweep_emit(
        const int* __restrict__ rank_g, const float* __restrict__ S,
        const float* __restrict__ bbox0, const float* __restrict__ bbox1,
        const float* __restrict__ bbox2,
        const float* __restrict__ kpt0, const float* __restrict__ kpt1,
        const float* __restrict__ kpt2,
        const float* __restrict__ vis0, const float* __restrict__ vis1,
        const float* __restrict__ vis2,
        float* __restrict__ out) {
    int n = blockIdx.x * 256 + threadIdx.x;
    int b = blockIdx.y;
    bool valid = (n < NANCH);
    int r = valid ? rank_g[(size_t)b * NANCH + n] : -1;
    if (__ballot(r >= 0) == 0ULL) return;   // wave-uniform skip (~15% of waves)

    int nc = valid ? n : 0;
    int nl, W, HW; float s;
    const float *bb, *kp, *vp;
    if (nc < N0) {
        nl = nc;            W = 160; HW = N0; s = 8.f;
        bb = bbox0; kp = kpt0; vp = vis0;
    } else if (nc < N0 + N1) {
        nl = nc - N0;       W = 80;  HW = N1; s = 16.f;
        bb = bbox1; kp = kpt1; vp = vis1;
    } else {
        nl = nc - N0 - N1;  W = 40;  HW = N2; s = 32.f;
        bb = bbox2; kp = kpt2; vp = vis2;
    }
    float px = (float)(nl % W) * s;
    float py = (float)(nl / W) * s;

    // coalesced loads for ALL lanes; stores predicated on r >= 0
    float score = S[(size_t)b * NANCH + nc];
    float bx = bb[((size_t)b * 4 + 0) * HW + nl];
    float by = bb[((size_t)b * 4 + 1) * HW + nl];
    float bw = bb[((size_t)b * 4 + 2) * HW + nl];
    float bh = bb[((size_t)b * 4 + 3) * HW + nl];
    if (r >= 0) {
        float cx = bx * s + px;
        float cy = by * s + py;
        float hw_ = expf(bw) * s * 0.5f;
        float hh  = expf(bh) * s * 0.5f;
        float* o = out + ((size_t)b * TOPK + r) * 5;
        o[0] = cx - hw_;
        o[1] = cy - hh;
        o[2] = cx + hw_;
        o[3] = cy + hh;
        o[4] = score;
    }
    float* ok = out + DETS_SIZE + ((size_t)b * TOPK + (size_t)(r < 0 ? 0 : r)) * 51;
    for (int k = 0; k < 17; ++k) {
        float xk = kp[((size_t)b * 34 + 2 * k    ) * HW + nl];
        float yk = kp[((size_t)b * 34 + 2 * k + 1) * HW + nl];
        float vv = vp[((size_t)b * 17 + k        ) * HW + nl];
        if (r >= 0) {
            ok[3 * k + 0] = xk * s + px;
            ok[3 * k + 1] = yk * s + py;
            ok[3 * k + 2] = 1.0f / (1.0f + expf(-vv));  // value-only: expf is fine
        }
    }
}

extern "C" void kernel_launch(void* const* d_in, const int* in_sizes, int n_in,
                              void* d_out, int out_size, void* d_ws, size_t ws_size,
                              hipStream_t stream) {
    const float* cls0  = (const float*)d_in[0];
    const float* cls1  = (const float*)d_in[1];
    const float* cls2  = (const float*)d_in[2];
    const float* bbox0 = (const float*)d_in[3];
    const float* bbox1 = (const float*)d_in[4];
    const float* bbox2 = (const float*)d_in[5];
    const float* obj0  = (const float*)d_in[6];
    const float* obj1  = (const float*)d_in[7];
    const float* obj2  = (const float*)d_in[8];
    const float* kpt0  = (const float*)d_in[9];
    const float* kpt1  = (const float*)d_in[10];
    const float* kpt2  = (const float*)d_in[11];
    const float* vis0  = (const float*)d_in[12];
    const float* vis1  = (const float*)d_in[13];
    const float* vis2  = (const float*)d_in[14];
    float* out = (float*)d_out;

    char* ws = (char*)d_ws;
    float*    S     = (float*)ws;   ws += (size_t)BATCH * NANCH * sizeof(float);
    int*      rank  = (int*)ws;     ws += (size_t)BATCH * NANCH * sizeof(int);
    unsigned* ghist = (unsigned*)ws;

    const int initN = BATCH * NANCH;
    init_kernel<<<(initN + 255) / 256, 256, 0, stream>>>(rank, ghist);

    dim3 gs((NANCH + SB - 1) / SB, BATCH);
    score_kernel<<<gs, 1024, 0, stream>>>(cls0, cls1, cls2, obj0, obj1, obj2, S, ghist);

    select_kernel<<<BATCH, 1024, 0, stream>>>(S, ghist, rank);

    dim3 ge((NANCH + 255) / 256, BATCH);
    sweep_emit<<<ge, 256, 0, stream>>>(rank, S,
        bbox0, bbox1, bbox2, kpt0, kpt1, kpt2, vis0, vis1, vis2, out);
}

// Round 5
// 309.441 us; speedup vs baseline: 1.3517x; 1.0025x over previous
//
#include <hip/hip_runtime.h>
#include <stdint.h>
#include <math.h>

#define BATCH 32
#define NANCH 33600
#define N0 25600   // 160x160, stride 8
#define N1 6400    // 80x80,  stride 16
#define N2 1600    // 40x40,  stride 32
#define TOPK 1000
#define NBIN 4096
#define CCAP 2816
#define SB 4096    // anchors per score block
#define DETS_SIZE (BATCH * TOPK * 5)

// numpy-exact float32 sigmoid: exp in double (correctly rounded to f32), then f32 divide.
// Needed ONLY where ranking depends on exact score bits.
__device__ __forceinline__ float sigmoid_np(float x) {
    float e = (float)::exp(-(double)x);
    return 1.0f / (1.0f + e);
}

// ---------------- Kernel 0: init rank table (-1) + global histogram (0) ----------------
__global__ void init_kernel(int* __restrict__ rank, unsigned* __restrict__ ghist) {
    int i = blockIdx.x * blockDim.x + threadIdx.x;
    if (i < BATCH * NANCH) rank[i] = -1;
    if (i < BATCH * NBIN) ghist[i] = 0u;
}

// ---------------- Kernel 1: score S = sigmoid(cls)*sigmoid(obj) + LDS histogram ---------
// Per-block 4096-bin LDS histogram, flushed with one global atomic per NON-ZERO bin.
// (Round-3 lesson: raw global atomics on clustered bins serialized cross-XCD -> 120 us.)
__global__ __launch_bounds__(1024) void score_kernel(
        const float* __restrict__ cls0, const float* __restrict__ cls1,
        const float* __restrict__ cls2,
        const float* __restrict__ obj0, const float* __restrict__ obj1,
        const float* __restrict__ obj2,
        float* __restrict__ S, unsigned* __restrict__ ghist) {
    __shared__ unsigned hist[NBIN];
    const int tid = threadIdx.x;
    const int b = blockIdx.y;
    const int base = blockIdx.x * SB;
    for (int i = tid; i < NBIN; i += 1024) hist[i] = 0u;
    __syncthreads();

    #pragma unroll
    for (int q = 0; q < SB / 1024; ++q) {
        int n = base + q * 1024 + tid;
        if (n < NANCH) {
            const float* cp; const float* op; int nl;
            if (n < N0)            { cp = cls0 + (size_t)b * N0; op = obj0 + (size_t)b * N0; nl = n; }
            else if (n < N0 + N1)  { cp = cls1 + (size_t)b * N1; op = obj1 + (size_t)b * N1; nl = n - N0; }
            else                   { cp = cls2 + (size_t)b * N2; op = obj2 + (size_t)b * N2; nl = n - N0 - N1; }
            float sc = sigmoid_np(cp[nl]) * sigmoid_np(op[nl]);
            S[(size_t)b * NANCH + n] = sc;
            atomicAdd(&hist[__float_as_uint(sc) >> 19], 1u);  // LDS atomic
        }
    }
    __syncthreads();
    for (int i = tid; i < NBIN; i += 1024) {
        unsigned c = hist[i];
        if (c) atomicAdd(&ghist[(size_t)b * NBIN + i], c);
    }
}

// ---------------- Kernel 2: exact top-1000 per batch -> rank[b][n] ------------------------
// 64-bit key = (score_bits << 32) | (0xFFFFFFFF - n): descending key order ==
// jax.lax.top_k order (descending score, ties by ascending index). Keys unique.
__global__ __launch_bounds__(1024) void select_kernel(const float* __restrict__ S_g,
                                                      const unsigned* __restrict__ ghist,
                                                      int* __restrict__ rank) {
    const int b = blockIdx.x;
    const float* S = S_g + (size_t)b * NANCH;
    __shared__ unsigned scan[1024];
    __shared__ unsigned long long wbuf[TOPK];
    __shared__ unsigned long long cbuf[CCAP];
    __shared__ unsigned sh_T, sh_above, sh_d, sh_k2, wcnt, ccnt;
    const int tid = threadIdx.x;

    if (tid == 0) { wcnt = 0u; ccnt = 0u; }
    // ---- load per-batch histogram (built by score_kernel), suffix-scan it ----
    unsigned s0 = ghist[(size_t)b * NBIN + 4 * tid + 0];
    unsigned s1 = ghist[(size_t)b * NBIN + 4 * tid + 1];
    unsigned s2 = ghist[(size_t)b * NBIN + 4 * tid + 2];
    unsigned s3 = ghist[(size_t)b * NBIN + 4 * tid + 3];
    unsigned tot = s0 + s1 + s2 + s3;
    scan[tid] = tot;
    __syncthreads();
    for (int off = 1; off < 1024; off <<= 1) {
        unsigned v = scan[tid] + ((tid + off < 1024) ? scan[tid + off] : 0u);
        __syncthreads();
        scan[tid] = v;
        __syncthreads();
    }
    unsigned excl = scan[tid] - tot;  // keys in bins > 4t+3
    {
        unsigned a3 = excl,      f3 = excl + s3;
        unsigned a2 = f3,        f2 = f3 + s2;
        unsigned a1 = f2,        f1 = f2 + s1;
        unsigned a0 = f1,        f0 = f1 + s0;
        if (a3 < TOPK && f3 >= TOPK) { sh_T = 4u * tid + 3u; sh_above = a3; }
        if (a2 < TOPK && f2 >= TOPK) { sh_T = 4u * tid + 2u; sh_above = a2; }
        if (a1 < TOPK && f1 >= TOPK) { sh_T = 4u * tid + 1u; sh_above = a1; }
        if (a0 < TOPK && f0 >= TOPK) { sh_T = 4u * tid + 0u; sh_above = a0; }
    }
    __syncthreads();
    const unsigned T = sh_T;
    const unsigned above = sh_above;     // strict winners (bins > T), < TOPK
    const unsigned need = TOPK - above;  // taken from boundary bin T

    // ---- single pass: collect strict winners + boundary candidates ----
    const float4* S4 = (const float4*)S;
    const int M4 = NANCH / 4;
    for (int i = tid; i < M4; i += 1024) {
        float4 v = S4[i];
        float c[4] = {v.x, v.y, v.z, v.w};
        #pragma unroll
        for (int q = 0; q < 4; ++q) {
            unsigned u = __float_as_uint(c[q]);
            unsigned bin = u >> 19;
            if (bin >= T) {
                unsigned n = (unsigned)(4 * i + q);
                unsigned long long key = ((unsigned long long)u << 32)
                                       | (unsigned long long)(0xFFFFFFFFu - n);
                if (bin > T) {
                    unsigned p = atomicAdd(&wcnt, 1u);
                    wbuf[p] = key;
                } else {
                    unsigned p = atomicAdd(&ccnt, 1u);
                    if (p < CCAP) cbuf[p] = key;
                }
            }
        }
    }
    __syncthreads();

    if (ccnt <= CCAP) {
        // ---- fast path: rank winners and candidates by LDS broadcast counting ----
        const int W = (int)wcnt;   // == above
        if (tid < W) {
            unsigned long long my = wbuf[tid];
            int r = 0;
            for (int j = 0; j < W; ++j) r += (wbuf[j] > my) ? 1 : 0;
            unsigned n = 0xFFFFFFFFu - (unsigned)(my & 0xFFFFFFFFULL);
            rank[(size_t)b * NANCH + n] = r;
        }
        const int C = (int)ccnt;
        if (tid < C) {
            unsigned long long my = cbuf[tid];
            int r = 0;
            for (int j = 0; j < C; ++j) r += (cbuf[j] > my) ? 1 : 0;
            if (r < (int)need) {
                unsigned n = 0xFFFFFFFFu - (unsigned)(my & 0xFFFFFFFFULL);
                rank[(size_t)b * NANCH + n] = (int)above + r;
            }
        }
    } else {
        // ---- fallback (boundary-bin overflow; not expected): 8x8-bit radix select ----
        unsigned long long prefix = 0ULL;
        unsigned k = TOPK;
        for (int pass = 7; pass >= 0; --pass) {
            if (tid < 256) scan[tid] = 0u;
            __syncthreads();
            const int shift = pass * 8;
            const unsigned long long prefmask =
                (pass == 7) ? 0ULL : (0xFFFFFFFFFFFFFFFFULL << (shift + 8));
            for (int i = tid; i < NANCH; i += 1024) {
                unsigned u = __float_as_uint(S[i]);
                unsigned long long key = ((unsigned long long)u << 32)
                                       | (unsigned long long)(0xFFFFFFFFu - (unsigned)i);
                if ((key & prefmask) == prefix)
                    atomicAdd(&scan[(unsigned)((key >> shift) & 0xFFULL)], 1u);
            }
            __syncthreads();
            if (tid == 0) {
                unsigned cum = 0; int d = 0;
                for (int v = 255; v >= 0; --v) {
                    unsigned c = scan[v];
                    if (cum + c >= k) { d = v; break; }
                    cum += c;
                }
                sh_d = (unsigned)d;
                sh_k2 = k - cum;
            }
            __syncthreads();
            prefix |= ((unsigned long long)sh_d) << shift;
            k = sh_k2;
            __syncthreads();
        }
        if (tid == 0) wcnt = 0u;
        __syncthreads();
        for (int i = tid; i < NANCH; i += 1024) {
            unsigned u = __float_as_uint(S[i]);
            unsigned long long key = ((unsigned long long)u << 32)
                                   | (unsigned long long)(0xFFFFFFFFu - (unsigned)i);
            if (key >= prefix) {
                unsigned pos = atomicAdd(&wcnt, 1u);
                wbuf[pos] = key;
            }
        }
        __syncthreads();
        const int m = (int)wcnt;   // == TOPK
        if (tid < m) {
            unsigned long long my = wbuf[tid];
            int r = 0;
            for (int j = 0; j < m; ++j) r += (wbuf[j] > my) ? 1 : 0;
            unsigned n = 0xFFFFFFFFu - (unsigned)(my & 0xFFFFFFFFULL);
            rank[(size_t)b * NANCH + n] = r;
        }
    }
}

// ---------------- Kernel 3: in-order predicated gather decode ----------------------------
// Round-4 lesson: unconditional streaming loads read ~205 MB of lines for ~3% kept
// lanes. Exec-masked loads (inside `if (r>=0)`) fetch ONLY kept lanes' cache lines
// (~91 MB of unique lines) while keeping ascending-address order for DRAM locality.
__global__ __launch_bounds__(256) void sweep_emit(
        const int* __restrict__ rank_g, const float* __restrict__ S,
        const float* __restrict__ bbox0, const float* __restrict__ bbox1,
        const float* __restrict__ bbox2,
        const float* __restrict__ kpt0, const float* __restrict__ kpt1,
        const float* __restrict__ kpt2,
        const float* __restrict__ vis0, const float* __restrict__ vis1,
        const float* __restrict__ vis2,
        float* __restrict__ out) {
    int n = blockIdx.x * 256 + threadIdx.x;
    int b = blockIdx.y;
    bool valid = (n < NANCH);
    int r = valid ? rank_g[(size_t)b * NANCH + n] : -1;
    if (__ballot(r >= 0) == 0ULL) return;   // wave-uniform skip (~15% of waves)
    if (r < 0) return;                      // exec-mask: only kept lanes load/store

    int nl, W, HW; float s;
    const float *bb, *kp, *vp;
    if (n < N0) {
        nl = n;            W = 160; HW = N0; s = 8.f;
        bb = bbox0; kp = kpt0; vp = vis0;
    } else if (n < N0 + N1) {
        nl = n - N0;       W = 80;  HW = N1; s = 16.f;
        bb = bbox1; kp = kpt1; vp = vis1;
    } else {
        nl = n - N0 - N1;  W = 40;  HW = N2; s = 32.f;
        bb = bbox2; kp = kpt2; vp = vis2;
    }
    float px = (float)(nl % W) * s;
    float py = (float)(nl / W) * s;

    float score = S[(size_t)b * NANCH + n];
    float bx = bb[((size_t)b * 4 + 0) * HW + nl];
    float by = bb[((size_t)b * 4 + 1) * HW + nl];
    float bw = bb[((size_t)b * 4 + 2) * HW + nl];
    float bh = bb[((size_t)b * 4 + 3) * HW + nl];
    {
        float cx = bx * s + px;
        float cy = by * s + py;
        float hw_ = expf(bw) * s * 0.5f;
        float hh  = expf(bh) * s * 0.5f;
        float* o = out + ((size_t)b * TOPK + r) * 5;
        o[0] = cx - hw_;
        o[1] = cy - hh;
        o[2] = cx + hw_;
        o[3] = cy + hh;
        o[4] = score;
    }
    float* ok = out + DETS_SIZE + ((size_t)b * TOPK + (size_t)r) * 51;
    #pragma unroll
    for (int k = 0; k < 17; ++k) {
        float xk = kp[((size_t)b * 34 + 2 * k    ) * HW + nl];
        float yk = kp[((size_t)b * 34 + 2 * k + 1) * HW + nl];
        float vv = vp[((size_t)b * 17 + k        ) * HW + nl];
        ok[3 * k + 0] = xk * s + px;
        ok[3 * k + 1] = yk * s + py;
        ok[3 * k + 2] = 1.0f / (1.0f + expf(-vv));  // value-only: expf is fine
    }
}

extern "C" void kernel_launch(void* const* d_in, const int* in_sizes, int n_in,
                              void* d_out, int out_size, void* d_ws, size_t ws_size,
                              hipStream_t stream) {
    const float* cls0  = (const float*)d_in[0];
    const float* cls1  = (const float*)d_in[1];
    const float* cls2  = (const float*)d_in[2];
    const float* bbox0 = (const float*)d_in[3];
    const float* bbox1 = (const float*)d_in[4];
    const float* bbox2 = (const float*)d_in[5];
    const float* obj0  = (const float*)d_in[6];
    const float* obj1  = (const float*)d_in[7];
    const float* obj2  = (const float*)d_in[8];
    const float* kpt0  = (const float*)d_in[9];
    const float* kpt1  = (const float*)d_in[10];
    const float* kpt2  = (const float*)d_in[11];
    const float* vis0  = (const float*)d_in[12];
    const float* vis1  = (const float*)d_in[13];
    const float* vis2  = (const float*)d_in[14];
    float* out = (float*)d_out;

    char* ws = (char*)d_ws;
    float*    S     = (float*)ws;   ws += (size_t)BATCH * NANCH * sizeof(float);
    int*      rank  = (int*)ws;     ws += (size_t)BATCH * NANCH * sizeof(int);
    unsigned* ghist = (unsigned*)ws;

    const int initN = BATCH * NANCH;
    init_kernel<<<(initN + 255) / 256, 256, 0, stream>>>(rank, ghist);

    dim3 gs((NANCH + SB - 1) / SB, BATCH);
    score_kernel<<<gs, 1024, 0, stream>>>(cls0, cls1, cls2, obj0, obj1, obj2, S, ghist);

    select_kernel<<<BATCH, 1024, 0, stream>>>(S, ghist, rank);

    dim3 ge((NANCH + 255) / 256, BATCH);
    sweep_emit<<<ge, 256, 0, stream>>>(rank, S,
        bbox0, bbox1, bbox2, kpt0, kpt1, kpt2, vis0, vis1, vis2, out);
}